// Round 5
// baseline (306.218 us; speedup 1.0000x reference)
//
#include <hip/hip_runtime.h>

#define HW 1024
#define TWO_PI_F 6.28318530717958647692f
#define NSLOT 64   // atomic spreading: 64 slots per accumulator, 5 accumulators

__device__ __forceinline__ float2 cmulf(float2 a, float2 b){
  return make_float2(a.x*b.x - a.y*b.y, a.x*b.y + a.y*b.x);
}

// fast atan2: octant reduction + 9th-order odd minimax poly, max err ~1e-4 rad.
__device__ __forceinline__ float fast_atan2f(float y, float x){
  float ax = fabsf(x), ay = fabsf(y);
  float mx = fmaxf(ax, ay), mn = fminf(ax, ay);
  float a  = mn * __builtin_amdgcn_rcpf(fmaxf(mx, 1e-37f));
  float s  = a * a;
  float r  = ((((0.0208351f*s - 0.085133f)*s + 0.180141f)*s - 0.3302995f)*s
              + 0.999866f) * a;
  r = (ay > ax) ? 1.57079632679f - r : r;
  r = (x < 0.f) ? 3.14159265359f - r : r;
  return (y < 0.f) ? -r : r;
}

// 256-thread block reduction (4 waves of 64), float
__device__ __forceinline__ float block_reduce_add_f(float v, float* sc){
  int tid = threadIdx.x;
  #pragma unroll
  for (int o = 32; o > 0; o >>= 1) v += __shfl_down(v, o, 64);
  __syncthreads();
  if ((tid & 63) == 0) sc[tid >> 6] = v;
  __syncthreads();
  return sc[0] + sc[1] + sc[2] + sc[3];
}

__global__ void zero_acc_kernel(double* acc){
  int i = threadIdx.x + blockIdx.x * blockDim.x;
  if (i < 5 * NSLOT) acc[i] = 0.0;
}

// twiddle table: tw[i] = exp(-2*pi*i*j/1024), i in [0,512) — constant per launch
__global__ void init_tw_kernel(float2* twg){
  int i = threadIdx.x + blockIdx.x * 256;
  if (i < 512){
    float s, c; sincosf(-TWO_PI_F * (float)i * (1.f/1024.f), &s, &c);
    twg[i] = make_float2(c, s);
  }
}

// ---------------------------------------------------------------------------
// Spatial half: 32x32 output tile per block, 4 vertically-consecutive pixels
// per thread. Rolling 3x3 register windows; bit-packed mask rows. pmg overlays
// the mask float-staging buffer (dead after packing) to cut LDS -> occupancy.
// acc rows: 0=grad numerator, 1=smooth, 2=slope (each NSLOT wide)
// ---------------------------------------------------------------------------
__global__ __launch_bounds__(256)
void spatial_kernel(const float* __restrict__ pred, const float* __restrict__ targ,
                    const float* __restrict__ mask, double* __restrict__ acc){
  __shared__ float sp[36*37];    // pred, halo 2, padded stride 37
  __shared__ float st[36*37];    // target
  __shared__ float poolA[38*39]; // mask float staging; later reused as pmg
  __shared__ float tmg[34*35];   // target grad magnitude, halo 1, stride 35
  __shared__ unsigned long long mrow[38]; // bit-packed mask rows
  __shared__ float sc[4];
  float* smkf = poolA;           // [38*39], live until packing
  float* pmg  = poolA;           // [34*35], live after the post-pack barrier

  const int tid = threadIdx.x;
  const int x0 = blockIdx.x << 5, y0 = blockIdx.y << 5;
  const size_t ib = (size_t)blockIdx.z * ((size_t)HW * HW);

  // load pred/target with halo 2 (zero outside image)
  for (int i = tid; i < 1296; i += 256){
    int a = i / 36, b = i % 36;
    int gy = y0 - 2 + a, gx = x0 - 2 + b;
    float pv = 0.f, tv = 0.f;
    if ((unsigned)gy < HW && (unsigned)gx < HW){
      size_t idx = ib + (size_t)gy * HW + gx;
      pv = pred[idx]; tv = targ[idx];
    }
    sp[a*37+b] = pv; st[a*37+b] = tv;
  }
  // load mask with halo 3 (coalesced float staging)
  for (int i = tid; i < 1444; i += 256){
    int a = i / 38, b = i % 38;
    int gy = y0 - 3 + a, gx = x0 - 3 + b;
    float v = 0.f;
    if ((unsigned)gy < HW && (unsigned)gx < HW) v = mask[ib + (size_t)gy * HW + gx];
    smkf[a*39+b] = v;
  }
  __syncthreads();

  // pack mask rows into bits (mask values are exact 0/1)
  if (tid < 38){
    unsigned long long w = 0ull;
    #pragma unroll
    for (int x = 0; x < 38; x++)
      w |= (smkf[tid*39 + x] > 0.5f) ? (1ull << x) : 0ull;
    mrow[tid] = w;
  }
  __syncthreads();   // smkf dead; pmg may now overwrite poolA

  // gradient-magnitude prepass over halo-1 region (34x34). OOB entries must be
  // exactly 0 (conv zero-pads p_mag itself), not sqrt(1e-8).
  for (int i = tid; i < 1156; i += 256){
    int iy = i / 34, ix = i % 34;
    int gy = y0 - 1 + iy, gx = x0 - 1 + ix;
    float pv = 0.f, tv = 0.f;
    if ((unsigned)gy < HW && (unsigned)gx < HW){
      int o = (iy)*37 + ix;
      float a00=sp[o], a01=sp[o+1], a02=sp[o+2];
      float a10=sp[o+37],           a12=sp[o+39];
      float a20=sp[o+74], a21=sp[o+75], a22=sp[o+76];
      float gxp = (a02 + 2.f*a12 + a22) - (a00 + 2.f*a10 + a20);
      float gyp = (a20 + 2.f*a21 + a22) - (a00 + 2.f*a01 + a02);
      pv = sqrtf(gxp*gxp + gyp*gyp + 1e-8f);
      float b00=st[o], b01=st[o+1], b02=st[o+2];
      float b10=st[o+37],           b12=st[o+39];
      float b20=st[o+74], b21=st[o+75], b22=st[o+76];
      float gxt = (b02 + 2.f*b12 + b22) - (b00 + 2.f*b10 + b20);
      float gyt = (b20 + 2.f*b21 + b22) - (b00 + 2.f*b01 + b02);
      tv = sqrtf(gxt*gxt + gyt*gyt + 1e-8f);
    }
    pmg[iy*35+ix] = pv; tmg[iy*35+ix] = tv;
  }
  __syncthreads();

  const int ty = tid >> 5, tx = tid & 31;
  const int r0 = ty << 2;            // first of 4 pixel rows for this thread

  // per-row mask popcounts for the 10 mask rows covering the 4 pixel windows
  int c1[10], c2[10], c3[10];
  #pragma unroll
  for (int j = 0; j < 10; j++){
    unsigned w = (unsigned)(mrow[r0 + j] >> tx);
    c3[j] = __popc(w & 0x7Fu);
    c2[j] = __popc((w >> 1) & 0x1Fu);
    c1[j] = __popc((w >> 2) & 0x7u);
  }

  // rolling 3x3 windows: P/Q over sp/st (rows r+1..r+3), A/B over pmg/tmg (r..r+2)
  float P[3][3], Q[3][3], A[3][3], B[3][3];
  #pragma unroll
  for (int rr = 0; rr < 3; rr++)
    #pragma unroll
    for (int cc = 0; cc < 3; cc++){
      P[rr][cc] = sp[(r0+1+rr)*37 + tx+1+cc];
      Q[rr][cc] = st[(r0+1+rr)*37 + tx+1+cc];
      A[rr][cc] = pmg[(r0+rr)*35 + tx+cc];
      B[rr][cc] = tmg[(r0+rr)*35 + tx+cc];
    }

  float accg = 0.f, accs = 0.f, accl = 0.f;
  #pragma unroll
  for (int k = 0; k < 4; k++){
    if (k){
      #pragma unroll
      for (int cc = 0; cc < 3; cc++){
        P[0][cc]=P[1][cc]; P[1][cc]=P[2][cc]; P[2][cc]=sp[(r0+k+3)*37 + tx+1+cc];
        Q[0][cc]=Q[1][cc]; Q[1][cc]=Q[2][cc]; Q[2][cc]=st[(r0+k+3)*37 + tx+1+cc];
        A[0][cc]=A[1][cc]; A[1][cc]=A[2][cc]; A[2][cc]=pmg[(r0+k+2)*35 + tx+cc];
        B[0][cc]=B[1][cc]; B[1][cc]=B[2][cc]; B[2][cc]=tmg[(r0+k+2)*35 + tx+cc];
      }
    }
    float gxp = (P[0][2]+2.f*P[1][2]+P[2][2]) - (P[0][0]+2.f*P[1][0]+P[2][0]);
    float gyp = (P[2][0]+2.f*P[2][1]+P[2][2]) - (P[0][0]+2.f*P[0][1]+P[0][2]);
    float cvp = 4.f*P[1][1] - P[0][1] - P[1][0] - P[1][2] - P[2][1];
    float gxt = (Q[0][2]+2.f*Q[1][2]+Q[2][2]) - (Q[0][0]+2.f*Q[1][0]+Q[2][0]);
    float gyt = (Q[2][0]+2.f*Q[2][1]+Q[2][2]) - (Q[0][0]+2.f*Q[0][1]+Q[0][2]);
    float cvt = 4.f*Q[1][1] - Q[0][1] - Q[1][0] - Q[1][2] - Q[2][1];

    float sd = fabsf(A[1][1] - B[1][1]);
    float x1 = gxp + 1e-8f, y1 = gyp;
    float x2 = gxt + 1e-8f, y2 = gyt;
    float dd = fabsf(fast_atan2f(y1*x2 - x1*y2, x1*x2 + y1*y2));
    float cd = fabsf(cvp - cvt);

    int s1 = c1[k+2]+c1[k+3]+c1[k+4];
    int s2 = c2[k+1]+c2[k+2]+c2[k+3]+c2[k+4]+c2[k+5];
    int s3 = c3[k]+c3[k+1]+c3[k+2]+c3[k+3]+c3[k+4]+c3[k+5]+c3[k+6];
    float w1 = (s1 > 0 && s1 <  9) ? 1.f : 0.f;
    float w2 = (s2 > 0 && s2 < 25) ? 1.f : 0.f;
    float w3 = (s3 > 0 && s3 < 49) ? 1.f : 0.f;

    accg += (sd + dd) * (w1 + 0.5f*(w2 + w3)) + cd * (2.f*w1 + w2 + w3);

    float s9 = 0.f, s9q = 0.f;
    #pragma unroll
    for (int rr = 0; rr < 3; rr++)
      #pragma unroll
      for (int cc = 0; cc < 3; cc++){ s9 += P[rr][cc]; s9q += P[rr][cc]*P[rr][cc]; }
    float lm = s9 * (1.f/9.f), lq = s9q * (1.f/9.f);
    accs += sqrtf(fmaxf(lq - lm*lm, 1e-8f)) * w1;

    float psx = (A[0][2]+2.f*A[1][2]+A[2][2]) - (A[0][0]+2.f*A[1][0]+A[2][0]);
    float psy = (A[2][0]+2.f*A[2][1]+A[2][2]) - (A[0][0]+2.f*A[0][1]+A[0][2]);
    float pch = sqrtf(psx*psx + psy*psy + 1e-8f);
    float tsx = (B[0][2]+2.f*B[1][2]+B[2][2]) - (B[0][0]+2.f*B[1][0]+B[2][0]);
    float tsy = (B[2][0]+2.f*B[2][1]+B[2][2]) - (B[0][0]+2.f*B[0][1]+B[0][2]);
    float tch = sqrtf(tsx*tsx + tsy*tsy + 1e-8f);
    accl += fabsf(pch - tch) * w1;
  }

  float g  = block_reduce_add_f(accg, sc);
  float sm = block_reduce_add_f(accs, sc);
  float sl = block_reduce_add_f(accl, sc);
  if (tid == 0){
    int slot = (blockIdx.x + blockIdx.y * 7 + blockIdx.z * 13) & (NSLOT - 1);
    atomicAdd(&acc[0*NSLOT + slot], (double)g);
    atomicAdd(&acc[1*NSLOT + slot], (double)sm);
    atomicAdd(&acc[2*NSLOT + slot], (double)sl);
  }
}

// ---------------------------------------------------------------------------
// Radix-4 double-stage butterfly (two merged radix-2 DIT layers)
// ---------------------------------------------------------------------------
__device__ __forceinline__ void quad_butterfly(float2* buf, int i, int h,
                                               float2 w1, float2 w2){
  float2 a0 = buf[i], a1 = buf[i+h], a2 = buf[i+2*h], a3 = buf[i+3*h];
  float2 t  = cmulf(w1, a1);
  float2 b0 = make_float2(a0.x + t.x, a0.y + t.y);
  float2 b1 = make_float2(a0.x - t.x, a0.y - t.y);
  float2 u  = cmulf(w1, a3);
  float2 b2 = make_float2(a2.x + u.x, a2.y + u.y);
  float2 b3 = make_float2(a2.x - u.x, a2.y - u.y);
  float2 v  = cmulf(w2, b2);
  float2 z  = cmulf(w2, b3);
  float2 zz = make_float2(z.y, -z.x);        // (-i) * z
  buf[i]     = make_float2(b0.x + v.x,  b0.y + v.y);
  buf[i+2*h] = make_float2(b0.x - v.x,  b0.y - v.y);
  buf[i+h]   = make_float2(b1.x + zz.x, b1.y + zz.y);
  buf[i+3*h] = make_float2(b1.x - zz.x, b1.y - zz.y);
}

// ---------------------------------------------------------------------------
// FFT pass 1: two rows per block (independent quads per stage -> ILP),
// z = pred + i*target, twiddles loaded from precomputed global table.
// ---------------------------------------------------------------------------
__global__ __launch_bounds__(256)
void fft_rows_kernel(const float* __restrict__ pred, const float* __restrict__ targ,
                     float2* __restrict__ Z, const float2* __restrict__ twg,
                     int img0){
  __shared__ float2 b1[1024];
  __shared__ float2 b2[1024];
  __shared__ float2 tw[512];
  const int tid = threadIdx.x;
  const int row0 = blockIdx.x << 1;
  const size_t i0 = ((size_t)(img0 + blockIdx.y) * HW + row0) * HW;
  float2* zrow = Z + ((size_t)blockIdx.y * HW + row0) * HW;

  for (int i = tid; i < 512; i += 256) tw[i] = twg[i];
  #pragma unroll
  for (int j = 0; j < 4; j++){
    int e = tid + (j << 8);
    int r = __brev(e) >> 22;          // bit-reversed load
    b1[r] = make_float2(pred[i0 + e],      targ[i0 + e]);
    b2[r] = make_float2(pred[i0 + HW + e], targ[i0 + HW + e]);
  }
  __syncthreads();
  #pragma unroll
  for (int s = 0; s < 10; s += 2){
    int h = 1 << s;
    int grp = tid >> s;
    int pos = tid & (h - 1);
    int i = (grp << (s + 2)) + pos;
    float2 w1 = tw[pos << (9 - s)];
    float2 w2 = tw[pos << (8 - s)];
    quad_butterfly(b1, i, h, w1, w2);
    quad_butterfly(b2, i, h, w1, w2);
    __syncthreads();
  }
  #pragma unroll
  for (int j = 0; j < 4; j++){
    int e = tid + (j << 8);
    zrow[e]      = b1[e];
    zrow[HW + e] = b2[e];
  }
}

// ---------------------------------------------------------------------------
// In-place square transpose via 32x32 tile pairs
// ---------------------------------------------------------------------------
__global__ __launch_bounds__(256)
void transpose_kernel(float2* __restrict__ Z){
  const int ti = blockIdx.y, tj = blockIdx.x;
  if (tj < ti) return;
  __shared__ float2 A[32*33];
  __shared__ float2 B[32*33];
  float2* base = Z + (size_t)blockIdx.z * HW * HW;
  const int tx = threadIdx.x & 31, ty = threadIdx.x >> 5;
  const bool off = (ti != tj);
  #pragma unroll
  for (int k = 0; k < 4; k++){
    int r = ty + (k << 3);
    A[r*33+tx] = base[(size_t)(ti*32+r)*HW + tj*32+tx];
    if (off) B[r*33+tx] = base[(size_t)(tj*32+r)*HW + ti*32+tx];
  }
  __syncthreads();
  #pragma unroll
  for (int k = 0; k < 4; k++){
    int r = ty + (k << 3);
    base[(size_t)(tj*32+r)*HW + ti*32+tx] = A[tx*33+r];
    if (off) base[(size_t)(ti*32+r)*HW + tj*32+tx] = B[tx*33+r];
  }
}

// ---------------------------------------------------------------------------
// FFT pass 2 + frequency reduce. Partner row ap = (-a) mod 1024 supplies
// Z(-k) for the Hermitian unpack:
//   pf = (Z(k)+conj(Z(-k)))/2 ; tf = (Z(k)-conj(Z(-k)))/(2i)
// mag term via single sqrt: (|p|-|t|)^2 = p2 + t2 - 2*sqrt(p2*t2)
// ---------------------------------------------------------------------------
__device__ __forceinline__ void freq_contrib(float2 Zk, float2 Zm, int k1, int k2,
                                             float& ms, float& ps){
  int di = k1 - 512, dj = k2 - 512;
  if (di*di + dj*dj < 94372) return;         // dist > 307.2  <=>  r2 >= 94372
  float pr = 0.5f*(Zk.x + Zm.x);
  float pi = 0.5f*(Zk.y - Zm.y);
  float tr = 0.5f*(Zk.y + Zm.y);
  float ti = 0.5f*(Zm.x - Zk.x);
  float p2 = pr*pr + pi*pi;
  float t2 = tr*tr + ti*ti;
  ms += p2 + t2 - 2.f*sqrtf(p2*t2);
  float re = pr*tr + pi*ti;                  // Re(pf * conj(tf))
  float im = pi*tr - pr*ti;                  // Im(pf * conj(tf))
  float pd = fast_atan2f(im, re);            // wrapped phase difference
  ps += pd*pd;
}

__global__ __launch_bounds__(256)
void fft_cols_reduce_kernel(const float2* __restrict__ Z,
                            const float2* __restrict__ twg,
                            double* __restrict__ acc){
  __shared__ float2 b1[1024];
  __shared__ float2 b2[1024];
  __shared__ float2 tw[512];
  __shared__ float sc[4];
  const int tid = threadIdx.x;
  const int a  = blockIdx.x;                 // 0..512
  const int ap = (1024 - a) & 1023;
  const float2* base = Z + (size_t)blockIdx.y * HW * HW;

  for (int i = tid; i < 512; i += 256) tw[i] = twg[i];
  #pragma unroll
  for (int j = 0; j < 4; j++){
    int e = tid + (j << 8);
    int r = __brev(e) >> 22;
    b1[r] = base[(size_t)a  * HW + e];
    b2[r] = base[(size_t)ap * HW + e];
  }
  __syncthreads();
  #pragma unroll
  for (int s = 0; s < 10; s += 2){
    int h = 1 << s;
    int grp = tid >> s;
    int pos = tid & (h - 1);
    int i = (grp << (s + 2)) + pos;
    float2 w1 = tw[pos << (9 - s)];
    float2 w2 = tw[pos << (8 - s)];
    quad_butterfly(b1, i, h, w1, w2);
    quad_butterfly(b2, i, h, w1, w2);
    __syncthreads();
  }

  float ms = 0.f, ps = 0.f;
  const bool two = (a != ap);                // self-paired rows 0 and 512
  #pragma unroll
  for (int j = 0; j < 4; j++){
    int k  = tid + (j << 8);
    int km = (1024 - k) & 1023;
    freq_contrib(b1[k], b2[km], k, a, ms, ps);
    if (two) freq_contrib(b2[k], b1[km], k, ap, ms, ps);
  }
  ms = block_reduce_add_f(ms, sc);
  ps = block_reduce_add_f(ps, sc);
  if (tid == 0){
    int slot = (blockIdx.x + blockIdx.y * 11) & (NSLOT - 1);
    atomicAdd(&acc[3*NSLOT + slot], (double)ms);
    atomicAdd(&acc[4*NSLOT + slot], (double)ps);
  }
}

// ---------------------------------------------------------------------------
// Single wave of 64 threads: lane t owns slot t of each sum; butterfly-reduce.
// ---------------------------------------------------------------------------
__global__ void finalize_kernel(const double* __restrict__ acc, float* __restrict__ out){
  const int t = threadIdx.x;   // 64 threads
  double v[5];
  #pragma unroll
  for (int s = 0; s < 5; s++) v[s] = acc[s*NSLOT + t];
  #pragma unroll
  for (int o = 32; o > 0; o >>= 1)
    #pragma unroll
    for (int s = 0; s < 5; s++) v[s] += __shfl_down(v[s], o, 64);
  if (t == 0){
    const double inv = 1.0 / 8388608.0;      // mean over 8*1024*1024
    double grad   = v[0] * inv / 3.0;        // / len(bms)
    double smooth = v[1] * inv;
    double slope  = v[2] * inv;
    double freq   = (v[3] + 2.0 * v[4]) * inv;
    double total  = 2.0*grad + 1.5*freq + 3.0*smooth + 2.0*slope;
    out[0] = (float)total;
    out[1] = (float)grad;
    out[2] = (float)freq;
    out[3] = (float)smooth;
    out[4] = (float)slope;
  }
}

extern "C" void kernel_launch(void* const* d_in, const int* in_sizes, int n_in,
                              void* d_out, int out_size, void* d_ws, size_t ws_size,
                              hipStream_t stream){
  const float* pred = (const float*)d_in[0];
  const float* targ = (const float*)d_in[1];
  const float* mask = (const float*)d_in[2];
  double* acc = (double*)d_ws;                          // [0, 2560)
  float2* twg = (float2*)((char*)d_ws + 4096);          // [4096, 8192)
  float2* Z   = (float2*)((char*)d_ws + 8192);
  const size_t zimg = (size_t)HW * HW * sizeof(float2); // 8 MiB per image

  int cmax = 1;
  if (ws_size > 8192){
    size_t c = (ws_size - 8192) / zimg;
    if (c > 8) c = 8;
    if (c < 1) c = 1;
    cmax = (int)c;
  }

  zero_acc_kernel<<<2, 256, 0, stream>>>(acc);
  init_tw_kernel<<<2, 256, 0, stream>>>(twg);
  spatial_kernel<<<dim3(32, 32, 8), 256, 0, stream>>>(pred, targ, mask, acc);
  for (int i0 = 0; i0 < 8; i0 += cmax){
    int c = (8 - i0 < cmax) ? (8 - i0) : cmax;
    fft_rows_kernel<<<dim3(512, c), 256, 0, stream>>>(pred, targ, Z, twg, i0);
    transpose_kernel<<<dim3(32, 32, c), 256, 0, stream>>>(Z);
    fft_cols_reduce_kernel<<<dim3(513, c), 256, 0, stream>>>(Z, twg, acc);
  }
  finalize_kernel<<<1, 64, 0, stream>>>(acc, (float*)d_out);
}

// Round 6
// 300.388 us; speedup vs baseline: 1.0194x; 1.0194x over previous
//
#include <hip/hip_runtime.h>

#define HW 1024
#define TWO_PI_F 6.28318530717958647692f
#define NSLOT 64   // atomic spreading: 64 slots per accumulator, 5 accumulators

__device__ __forceinline__ float2 cmulf(float2 a, float2 b){
  return make_float2(a.x*b.x - a.y*b.y, a.x*b.y + a.y*b.x);
}

// fast atan2: octant reduction + 9th-order odd minimax poly, max err ~1e-4 rad.
__device__ __forceinline__ float fast_atan2f(float y, float x){
  float ax = fabsf(x), ay = fabsf(y);
  float mx = fmaxf(ax, ay), mn = fminf(ax, ay);
  float a  = mn * __builtin_amdgcn_rcpf(fmaxf(mx, 1e-37f));
  float s  = a * a;
  float r  = ((((0.0208351f*s - 0.085133f)*s + 0.180141f)*s - 0.3302995f)*s
              + 0.999866f) * a;
  r = (ay > ax) ? 1.57079632679f - r : r;
  r = (x < 0.f) ? 3.14159265359f - r : r;
  return (y < 0.f) ? -r : r;
}

// 256-thread block reduction (4 waves of 64), float
__device__ __forceinline__ float block_reduce_add_f(float v, float* sc){
  int tid = threadIdx.x;
  #pragma unroll
  for (int o = 32; o > 0; o >>= 1) v += __shfl_down(v, o, 64);
  __syncthreads();
  if ((tid & 63) == 0) sc[tid >> 6] = v;
  __syncthreads();
  return sc[0] + sc[1] + sc[2] + sc[3];
}

__global__ void zero_acc_kernel(double* acc){
  int i = threadIdx.x + blockIdx.x * blockDim.x;
  if (i < 5 * NSLOT) acc[i] = 0.0;
}

// twiddle table: twg[i] = exp(-2*pi*i*i_/1024), i in [0,512)
__global__ void init_tw_kernel(float2* twg){
  int i = threadIdx.x + blockIdx.x * 256;
  if (i < 512){
    float s, c; sincosf(-TWO_PI_F * (float)i * (1.f/1024.f), &s, &c);
    twg[i] = make_float2(c, s);
  }
}

// ---------------------------------------------------------------------------
// Spatial half (R4 structure, float reduce): 32x32 tile/block, 4 px/thread.
// ---------------------------------------------------------------------------
__global__ __launch_bounds__(256)
void spatial_kernel(const float* __restrict__ pred, const float* __restrict__ targ,
                    const float* __restrict__ mask, double* __restrict__ acc){
  __shared__ float sp[36*37];
  __shared__ float st[36*37];
  __shared__ float smkf[38*39];
  __shared__ unsigned long long mrow[38];
  __shared__ float pmg[34*35];
  __shared__ float tmg[34*35];
  __shared__ float sc[4];

  const int tid = threadIdx.x;
  const int x0 = blockIdx.x << 5, y0 = blockIdx.y << 5;
  const size_t ib = (size_t)blockIdx.z * ((size_t)HW * HW);

  for (int i = tid; i < 1296; i += 256){
    int a = i / 36, b = i % 36;
    int gy = y0 - 2 + a, gx = x0 - 2 + b;
    float pv = 0.f, tv = 0.f;
    if ((unsigned)gy < HW && (unsigned)gx < HW){
      size_t idx = ib + (size_t)gy * HW + gx;
      pv = pred[idx]; tv = targ[idx];
    }
    sp[a*37+b] = pv; st[a*37+b] = tv;
  }
  for (int i = tid; i < 1444; i += 256){
    int a = i / 38, b = i % 38;
    int gy = y0 - 3 + a, gx = x0 - 3 + b;
    float v = 0.f;
    if ((unsigned)gy < HW && (unsigned)gx < HW) v = mask[ib + (size_t)gy * HW + gx];
    smkf[a*39+b] = v;
  }
  __syncthreads();

  if (tid < 38){
    unsigned long long w = 0ull;
    #pragma unroll
    for (int x = 0; x < 38; x++)
      w |= (smkf[tid*39 + x] > 0.5f) ? (1ull << x) : 0ull;
    mrow[tid] = w;
  }

  for (int i = tid; i < 1156; i += 256){
    int iy = i / 34, ix = i % 34;
    int gy = y0 - 1 + iy, gx = x0 - 1 + ix;
    float pv = 0.f, tv = 0.f;
    if ((unsigned)gy < HW && (unsigned)gx < HW){
      int o = (iy)*37 + ix;
      float a00=sp[o], a01=sp[o+1], a02=sp[o+2];
      float a10=sp[o+37],           a12=sp[o+39];
      float a20=sp[o+74], a21=sp[o+75], a22=sp[o+76];
      float gxp = (a02 + 2.f*a12 + a22) - (a00 + 2.f*a10 + a20);
      float gyp = (a20 + 2.f*a21 + a22) - (a00 + 2.f*a01 + a02);
      pv = sqrtf(gxp*gxp + gyp*gyp + 1e-8f);
      float b00=st[o], b01=st[o+1], b02=st[o+2];
      float b10=st[o+37],           b12=st[o+39];
      float b20=st[o+74], b21=st[o+75], b22=st[o+76];
      float gxt = (b02 + 2.f*b12 + b22) - (b00 + 2.f*b10 + b20);
      float gyt = (b20 + 2.f*b21 + b22) - (b00 + 2.f*b01 + b02);
      tv = sqrtf(gxt*gxt + gyt*gyt + 1e-8f);
    }
    pmg[iy*35+ix] = pv; tmg[iy*35+ix] = tv;
  }
  __syncthreads();

  const int ty = tid >> 5, tx = tid & 31;
  const int r0 = ty << 2;

  int c1[10], c2[10], c3[10];
  #pragma unroll
  for (int j = 0; j < 10; j++){
    unsigned w = (unsigned)(mrow[r0 + j] >> tx);
    c3[j] = __popc(w & 0x7Fu);
    c2[j] = __popc((w >> 1) & 0x1Fu);
    c1[j] = __popc((w >> 2) & 0x7u);
  }

  float P[3][3], Q[3][3], A[3][3], B[3][3];
  #pragma unroll
  for (int rr = 0; rr < 3; rr++)
    #pragma unroll
    for (int cc = 0; cc < 3; cc++){
      P[rr][cc] = sp[(r0+1+rr)*37 + tx+1+cc];
      Q[rr][cc] = st[(r0+1+rr)*37 + tx+1+cc];
      A[rr][cc] = pmg[(r0+rr)*35 + tx+cc];
      B[rr][cc] = tmg[(r0+rr)*35 + tx+cc];
    }

  float accg = 0.f, accs = 0.f, accl = 0.f;
  #pragma unroll
  for (int k = 0; k < 4; k++){
    if (k){
      #pragma unroll
      for (int cc = 0; cc < 3; cc++){
        P[0][cc]=P[1][cc]; P[1][cc]=P[2][cc]; P[2][cc]=sp[(r0+k+3)*37 + tx+1+cc];
        Q[0][cc]=Q[1][cc]; Q[1][cc]=Q[2][cc]; Q[2][cc]=st[(r0+k+3)*37 + tx+1+cc];
        A[0][cc]=A[1][cc]; A[1][cc]=A[2][cc]; A[2][cc]=pmg[(r0+k+2)*35 + tx+cc];
        B[0][cc]=B[1][cc]; B[1][cc]=B[2][cc]; B[2][cc]=tmg[(r0+k+2)*35 + tx+cc];
      }
    }
    float gxp = (P[0][2]+2.f*P[1][2]+P[2][2]) - (P[0][0]+2.f*P[1][0]+P[2][0]);
    float gyp = (P[2][0]+2.f*P[2][1]+P[2][2]) - (P[0][0]+2.f*P[0][1]+P[0][2]);
    float cvp = 4.f*P[1][1] - P[0][1] - P[1][0] - P[1][2] - P[2][1];
    float gxt = (Q[0][2]+2.f*Q[1][2]+Q[2][2]) - (Q[0][0]+2.f*Q[1][0]+Q[2][0]);
    float gyt = (Q[2][0]+2.f*Q[2][1]+Q[2][2]) - (Q[0][0]+2.f*Q[0][1]+Q[0][2]);
    float cvt = 4.f*Q[1][1] - Q[0][1] - Q[1][0] - Q[1][2] - Q[2][1];

    float sd = fabsf(A[1][1] - B[1][1]);
    float x1 = gxp + 1e-8f, y1 = gyp;
    float x2 = gxt + 1e-8f, y2 = gyt;
    float dd = fabsf(fast_atan2f(y1*x2 - x1*y2, x1*x2 + y1*y2));
    float cd = fabsf(cvp - cvt);

    int s1 = c1[k+2]+c1[k+3]+c1[k+4];
    int s2 = c2[k+1]+c2[k+2]+c2[k+3]+c2[k+4]+c2[k+5];
    int s3 = c3[k]+c3[k+1]+c3[k+2]+c3[k+3]+c3[k+4]+c3[k+5]+c3[k+6];
    float w1 = (s1 > 0 && s1 <  9) ? 1.f : 0.f;
    float w2 = (s2 > 0 && s2 < 25) ? 1.f : 0.f;
    float w3 = (s3 > 0 && s3 < 49) ? 1.f : 0.f;

    accg += (sd + dd) * (w1 + 0.5f*(w2 + w3)) + cd * (2.f*w1 + w2 + w3);

    float s9 = 0.f, s9q = 0.f;
    #pragma unroll
    for (int rr = 0; rr < 3; rr++)
      #pragma unroll
      for (int cc = 0; cc < 3; cc++){ s9 += P[rr][cc]; s9q += P[rr][cc]*P[rr][cc]; }
    float lm = s9 * (1.f/9.f), lq = s9q * (1.f/9.f);
    accs += sqrtf(fmaxf(lq - lm*lm, 1e-8f)) * w1;

    float psx = (A[0][2]+2.f*A[1][2]+A[2][2]) - (A[0][0]+2.f*A[1][0]+A[2][0]);
    float psy = (A[2][0]+2.f*A[2][1]+A[2][2]) - (A[0][0]+2.f*A[0][1]+A[0][2]);
    float pch = sqrtf(psx*psx + psy*psy + 1e-8f);
    float tsx = (B[0][2]+2.f*B[1][2]+B[2][2]) - (B[0][0]+2.f*B[1][0]+B[2][0]);
    float tsy = (B[2][0]+2.f*B[2][1]+B[2][2]) - (B[0][0]+2.f*B[0][1]+B[0][2]);
    float tch = sqrtf(tsx*tsx + tsy*tsy + 1e-8f);
    accl += fabsf(pch - tch) * w1;
  }

  float g  = block_reduce_add_f(accg, sc);
  float sm = block_reduce_add_f(accs, sc);
  float sl = block_reduce_add_f(accl, sc);
  if (tid == 0){
    int slot = (blockIdx.x + blockIdx.y * 7 + blockIdx.z * 13) & (NSLOT - 1);
    atomicAdd(&acc[0*NSLOT + slot], (double)g);
    atomicAdd(&acc[1*NSLOT + slot], (double)sm);
    atomicAdd(&acc[2*NSLOT + slot], (double)sl);
  }
}

// ---------------------------------------------------------------------------
// Wave-level 1024-pt FFT: 1024 = 64 (cross-lane, shfl_xor DIT) x 16 (in-reg).
// Input: lane q, slot j holds x[j + 16*brev6(q)] (lane-bit-reversed chunks).
// Output: lane q, slot j holds X[q + 64*j] (natural order). No LDS, no barriers.
// ---------------------------------------------------------------------------
#define FC 0.70710678118654752f
#define FC1 0.92387953251128676f
#define FS1 0.38268343236508977f

__device__ __forceinline__ void bfly(float2& a, float2& b){
  float tx = b.x, ty = b.y;
  b.x = a.x - tx; b.y = a.y - ty;
  a.x += tx;      a.y += ty;
}
__device__ __forceinline__ void cmul_c(float2& b, float wr, float wi){
  float tx = wr*b.x - wi*b.y, ty = wr*b.y + wi*b.x;
  b.x = tx; b.y = ty;
}
__device__ __forceinline__ void rotmi(float2& b){   // b *= -i
  float t = b.x; b.x = b.y; b.y = -t;
}

__device__ __forceinline__ void fft16_reg(float2* v){
  float2 y[16];
  y[0]=v[0];  y[1]=v[8];  y[2]=v[4];  y[3]=v[12];
  y[4]=v[2];  y[5]=v[10]; y[6]=v[6];  y[7]=v[14];
  y[8]=v[1];  y[9]=v[9];  y[10]=v[5]; y[11]=v[13];
  y[12]=v[3]; y[13]=v[11];y[14]=v[7]; y[15]=v[15];
  #pragma unroll
  for (int g = 0; g < 8; g++) bfly(y[2*g], y[2*g+1]);
  #pragma unroll
  for (int g = 0; g < 4; g++){
    int b = 4*g;
    bfly(y[b], y[b+2]);
    rotmi(y[b+3]); bfly(y[b+1], y[b+3]);
  }
  #pragma unroll
  for (int g = 0; g < 2; g++){
    int b = 8*g;
    bfly(y[b], y[b+4]);
    cmul_c(y[b+5],  FC, -FC); bfly(y[b+1], y[b+5]);
    rotmi(y[b+6]);            bfly(y[b+2], y[b+6]);
    cmul_c(y[b+7], -FC, -FC); bfly(y[b+3], y[b+7]);
  }
  bfly(y[0], y[8]);
  cmul_c(y[9],   FC1, -FS1); bfly(y[1], y[9]);
  cmul_c(y[10],  FC,  -FC);  bfly(y[2], y[10]);
  cmul_c(y[11],  FS1, -FC1); bfly(y[3], y[11]);
  rotmi(y[12]);              bfly(y[4], y[12]);
  cmul_c(y[13], -FS1, -FC1); bfly(y[5], y[13]);
  cmul_c(y[14], -FC,  -FC);  bfly(y[6], y[14]);
  cmul_c(y[15], -FC1, -FS1); bfly(y[7], y[15]);
  #pragma unroll
  for (int j = 0; j < 16; j++) v[j] = y[j];
}

__device__ __forceinline__ void fft1024_wave(float2* v, int lane,
                                             const float2* __restrict__ twg){
  // cross-lane 64-pt DIT per slot
  #pragma unroll
  for (int s = 0; s < 6; s++){
    const int h = 1 << s;
    const bool up = (lane & h) != 0;
    float2 w = make_float2(1.f, 0.f);
    if (s > 0) w = twg[(lane & (h - 1)) << (9 - s)];
    #pragma unroll
    for (int j = 0; j < 16; j++){
      float ox = __shfl_xor(v[j].x, h, 64);
      float oy = __shfl_xor(v[j].y, h, 64);
      float cx = up ? v[j].x : ox;
      float cy = up ? v[j].y : oy;
      float tx, ty;
      if (s == 0){ tx = cx; ty = cy; }
      else { tx = w.x*cx - w.y*cy; ty = w.x*cy + w.y*cx; }
      v[j].x = up ? (ox - tx) : (v[j].x + tx);
      v[j].y = up ? (oy - ty) : (v[j].y + ty);
    }
  }
  // bridge twiddle: slot j *= exp(-2*pi*i * j*lane / 1024) = w_lane^j
  float2 wq = twg[lane];
  float2 cur = make_float2(1.f, 0.f);
  #pragma unroll
  for (int j = 1; j < 16; j++){
    cur = cmulf(cur, wq);
    v[j] = cmulf(v[j], cur);
  }
  // 16-pt FFT over slots
  fft16_reg(v);
}

// ---------------------------------------------------------------------------
// FFT pass 1: one wave per row (4 rows/block). z = pred + i*targ. Barrier-free.
// ---------------------------------------------------------------------------
__global__ __launch_bounds__(256)
void fft_rows_kernel(const float* __restrict__ pred, const float* __restrict__ targ,
                     float2* __restrict__ Z, const float2* __restrict__ twg,
                     int img0){
  const int lane = threadIdx.x & 63;
  const int wv = threadIdx.x >> 6;
  const int row = (blockIdx.x << 2) + wv;
  const size_t ibase = ((size_t)(img0 + blockIdx.y) * HW + row) * HW;
  const int rb = __brev(lane) >> 26;     // brev6(lane)
  const float4* p4 = (const float4*)(pred + ibase);
  const float4* t4 = (const float4*)(targ + ibase);
  float2 v[16];
  #pragma unroll
  for (int m = 0; m < 4; m++){
    float4 a = p4[4*rb + m];
    float4 b = t4[4*rb + m];
    v[4*m+0] = make_float2(a.x, b.x);
    v[4*m+1] = make_float2(a.y, b.y);
    v[4*m+2] = make_float2(a.z, b.z);
    v[4*m+3] = make_float2(a.w, b.w);
  }
  fft1024_wave(v, lane, twg);
  float2* zr = Z + ((size_t)blockIdx.y * HW + row) * HW;
  #pragma unroll
  for (int j = 0; j < 16; j++) zr[(j << 6) + lane] = v[j];
}

// ---------------------------------------------------------------------------
// In-place square transpose via 32x32 tile pairs (unchanged)
// ---------------------------------------------------------------------------
__global__ __launch_bounds__(256)
void transpose_kernel(float2* __restrict__ Z){
  const int ti = blockIdx.y, tj = blockIdx.x;
  if (tj < ti) return;
  __shared__ float2 A[32*33];
  __shared__ float2 B[32*33];
  float2* base = Z + (size_t)blockIdx.z * HW * HW;
  const int tx = threadIdx.x & 31, ty = threadIdx.x >> 5;
  const bool off = (ti != tj);
  #pragma unroll
  for (int k = 0; k < 4; k++){
    int r = ty + (k << 3);
    A[r*33+tx] = base[(size_t)(ti*32+r)*HW + tj*32+tx];
    if (off) B[r*33+tx] = base[(size_t)(tj*32+r)*HW + ti*32+tx];
  }
  __syncthreads();
  #pragma unroll
  for (int k = 0; k < 4; k++){
    int r = ty + (k << 3);
    base[(size_t)(tj*32+r)*HW + ti*32+tx] = A[tx*33+r];
    if (off) base[(size_t)(ti*32+r)*HW + tj*32+tx] = B[tx*33+r];
  }
}

// ---------------------------------------------------------------------------
// FFT pass 2 + reduce: one wave per row-pair (a, ap=-a mod 1024). Hermitian
// unpack via fixed cross-lane permutation: Z(-k) for k=q+64j lives at lane
// (64-q)&63 slot 15-j (lane 0: own slot (16-j)&15). Barrier-free.
// ---------------------------------------------------------------------------
__device__ __forceinline__ void freq_contrib(float2 Zk, float2 Zm, int k1, int k2,
                                             float& ms, float& ps){
  int di = k1 - 512, dj = k2 - 512;
  if (di*di + dj*dj < 94372) return;         // dist > 307.2  <=>  r2 >= 94372
  float pr = 0.5f*(Zk.x + Zm.x);
  float pi = 0.5f*(Zk.y - Zm.y);
  float tr = 0.5f*(Zk.y + Zm.y);
  float ti = 0.5f*(Zm.x - Zk.x);
  float p2 = pr*pr + pi*pi;
  float t2 = tr*tr + ti*ti;
  ms += p2 + t2 - 2.f*sqrtf(p2*t2);
  float re = pr*tr + pi*ti;
  float im = pi*tr - pr*ti;
  float pd = fast_atan2f(im, re);
  ps += pd*pd;
}

__global__ __launch_bounds__(256)
void fft_cols_reduce_kernel(const float2* __restrict__ Z,
                            const float2* __restrict__ twg,
                            double* __restrict__ acc){
  const int lane = threadIdx.x & 63;
  const int wv = threadIdx.x >> 6;
  const int a = (blockIdx.x << 2) + wv;
  if (a > 512) return;                       // wave-uniform
  const int ap = (1024 - a) & 1023;
  const float2* base = Z + (size_t)blockIdx.y * HW * HW;
  const int rb = __brev(lane) >> 26;

  float2 va[16], vb[16];
  const float4* ra = (const float4*)(base + (size_t)a  * HW);
  const float4* rp = (const float4*)(base + (size_t)ap * HW);
  #pragma unroll
  for (int m = 0; m < 8; m++){
    float4 x = ra[8*rb + m];
    va[2*m]   = make_float2(x.x, x.y);
    va[2*m+1] = make_float2(x.z, x.w);
    float4 yv = rp[8*rb + m];
    vb[2*m]   = make_float2(yv.x, yv.y);
    vb[2*m+1] = make_float2(yv.z, yv.w);
  }
  fft1024_wave(va, lane, twg);
  fft1024_wave(vb, lane, twg);

  float ms = 0.f, ps = 0.f;
  const bool two = (a != ap);
  const int qm = (64 - lane) & 63;
  #pragma unroll
  for (int j = 0; j < 16; j++){
    int k = lane + (j << 6);
    float2 shb = make_float2(__shfl(vb[15-j].x, qm, 64), __shfl(vb[15-j].y, qm, 64));
    float2 vbm = (lane == 0) ? vb[(16-j) & 15] : shb;
    freq_contrib(va[j], vbm, k, a, ms, ps);
    if (two){
      float2 sha = make_float2(__shfl(va[15-j].x, qm, 64), __shfl(va[15-j].y, qm, 64));
      float2 vam = (lane == 0) ? va[(16-j) & 15] : sha;
      freq_contrib(vb[j], vam, k, ap, ms, ps);
    }
  }
  #pragma unroll
  for (int o = 32; o > 0; o >>= 1){
    ms += __shfl_down(ms, o, 64);
    ps += __shfl_down(ps, o, 64);
  }
  if (lane == 0){
    int slot = ((blockIdx.x << 2) + wv + blockIdx.y * 11) & (NSLOT - 1);
    atomicAdd(&acc[3*NSLOT + slot], (double)ms);
    atomicAdd(&acc[4*NSLOT + slot], (double)ps);
  }
}

// ---------------------------------------------------------------------------
__global__ void finalize_kernel(const double* __restrict__ acc, float* __restrict__ out){
  const int t = threadIdx.x;   // 64 threads
  double v[5];
  #pragma unroll
  for (int s = 0; s < 5; s++) v[s] = acc[s*NSLOT + t];
  #pragma unroll
  for (int o = 32; o > 0; o >>= 1)
    #pragma unroll
    for (int s = 0; s < 5; s++) v[s] += __shfl_down(v[s], o, 64);
  if (t == 0){
    const double inv = 1.0 / 8388608.0;      // mean over 8*1024*1024
    double grad   = v[0] * inv / 3.0;        // / len(bms)
    double smooth = v[1] * inv;
    double slope  = v[2] * inv;
    double freq   = (v[3] + 2.0 * v[4]) * inv;
    double total  = 2.0*grad + 1.5*freq + 3.0*smooth + 2.0*slope;
    out[0] = (float)total;
    out[1] = (float)grad;
    out[2] = (float)freq;
    out[3] = (float)smooth;
    out[4] = (float)slope;
  }
}

extern "C" void kernel_launch(void* const* d_in, const int* in_sizes, int n_in,
                              void* d_out, int out_size, void* d_ws, size_t ws_size,
                              hipStream_t stream){
  const float* pred = (const float*)d_in[0];
  const float* targ = (const float*)d_in[1];
  const float* mask = (const float*)d_in[2];
  double* acc = (double*)d_ws;                          // [0, 2560)
  float2* twg = (float2*)((char*)d_ws + 4096);          // [4096, 8192)
  float2* Z   = (float2*)((char*)d_ws + 8192);
  const size_t zimg = (size_t)HW * HW * sizeof(float2); // 8 MiB per image

  int cmax = 1;
  if (ws_size > 8192){
    size_t c = (ws_size - 8192) / zimg;
    if (c > 8) c = 8;
    if (c < 1) c = 1;
    cmax = (int)c;
  }

  zero_acc_kernel<<<2, 256, 0, stream>>>(acc);
  init_tw_kernel<<<2, 256, 0, stream>>>(twg);
  spatial_kernel<<<dim3(32, 32, 8), 256, 0, stream>>>(pred, targ, mask, acc);
  for (int i0 = 0; i0 < 8; i0 += cmax){
    int c = (8 - i0 < cmax) ? (8 - i0) : cmax;
    fft_rows_kernel<<<dim3(256, c), 256, 0, stream>>>(pred, targ, Z, twg, i0);
    transpose_kernel<<<dim3(32, 32, c), 256, 0, stream>>>(Z);
    fft_cols_reduce_kernel<<<dim3(129, c), 256, 0, stream>>>(Z, twg, acc);
  }
  finalize_kernel<<<1, 64, 0, stream>>>(acc, (float*)d_out);
}

// Round 7
// 285.048 us; speedup vs baseline: 1.0743x; 1.0538x over previous
//
#include <hip/hip_runtime.h>

#define HW 1024
#define TWO_PI_F 6.28318530717958647692f
#define NSLOT 64   // atomic spreading: 64 slots per accumulator, 5 accumulators

__device__ __forceinline__ float2 cmulf(float2 a, float2 b){
  return make_float2(a.x*b.x - a.y*b.y, a.x*b.y + a.y*b.x);
}

// fast atan2: octant reduction + 9th-order odd minimax poly, max err ~1e-4 rad.
__device__ __forceinline__ float fast_atan2f(float y, float x){
  float ax = fabsf(x), ay = fabsf(y);
  float mx = fmaxf(ax, ay), mn = fminf(ax, ay);
  float a  = mn * __builtin_amdgcn_rcpf(fmaxf(mx, 1e-37f));
  float s  = a * a;
  float r  = ((((0.0208351f*s - 0.085133f)*s + 0.180141f)*s - 0.3302995f)*s
              + 0.999866f) * a;
  r = (ay > ax) ? 1.57079632679f - r : r;
  r = (x < 0.f) ? 3.14159265359f - r : r;
  return (y < 0.f) ? -r : r;
}

// 256-thread block reduction (4 waves of 64), float
__device__ __forceinline__ float block_reduce_add_f(float v, float* sc){
  int tid = threadIdx.x;
  #pragma unroll
  for (int o = 32; o > 0; o >>= 1) v += __shfl_down(v, o, 64);
  __syncthreads();
  if ((tid & 63) == 0) sc[tid >> 6] = v;
  __syncthreads();
  return sc[0] + sc[1] + sc[2] + sc[3];
}

// merged setup: zero accumulators + twiddle table (one launch)
__global__ void setup_kernel(double* acc, float2* twg){
  int i = threadIdx.x + blockIdx.x * 256;   // grid 2 x 256 -> 0..511
  if (i < 5 * NSLOT) acc[i] = 0.0;
  if (i < 512){
    float s, c; sincosf(-TWO_PI_F * (float)i * (1.f/1024.f), &s, &c);
    twg[i] = make_float2(c, s);
  }
}

// ---------------------------------------------------------------------------
// Spatial half (unchanged from R4/R6): 32x32 tile/block, 4 px/thread.
// ---------------------------------------------------------------------------
__global__ __launch_bounds__(256)
void spatial_kernel(const float* __restrict__ pred, const float* __restrict__ targ,
                    const float* __restrict__ mask, double* __restrict__ acc){
  __shared__ float sp[36*37];
  __shared__ float st[36*37];
  __shared__ float smkf[38*39];
  __shared__ unsigned long long mrow[38];
  __shared__ float pmg[34*35];
  __shared__ float tmg[34*35];
  __shared__ float sc[4];

  const int tid = threadIdx.x;
  const int x0 = blockIdx.x << 5, y0 = blockIdx.y << 5;
  const size_t ib = (size_t)blockIdx.z * ((size_t)HW * HW);

  for (int i = tid; i < 1296; i += 256){
    int a = i / 36, b = i % 36;
    int gy = y0 - 2 + a, gx = x0 - 2 + b;
    float pv = 0.f, tv = 0.f;
    if ((unsigned)gy < HW && (unsigned)gx < HW){
      size_t idx = ib + (size_t)gy * HW + gx;
      pv = pred[idx]; tv = targ[idx];
    }
    sp[a*37+b] = pv; st[a*37+b] = tv;
  }
  for (int i = tid; i < 1444; i += 256){
    int a = i / 38, b = i % 38;
    int gy = y0 - 3 + a, gx = x0 - 3 + b;
    float v = 0.f;
    if ((unsigned)gy < HW && (unsigned)gx < HW) v = mask[ib + (size_t)gy * HW + gx];
    smkf[a*39+b] = v;
  }
  __syncthreads();

  if (tid < 38){
    unsigned long long w = 0ull;
    #pragma unroll
    for (int x = 0; x < 38; x++)
      w |= (smkf[tid*39 + x] > 0.5f) ? (1ull << x) : 0ull;
    mrow[tid] = w;
  }

  for (int i = tid; i < 1156; i += 256){
    int iy = i / 34, ix = i % 34;
    int gy = y0 - 1 + iy, gx = x0 - 1 + ix;
    float pv = 0.f, tv = 0.f;
    if ((unsigned)gy < HW && (unsigned)gx < HW){
      int o = (iy)*37 + ix;
      float a00=sp[o], a01=sp[o+1], a02=sp[o+2];
      float a10=sp[o+37],           a12=sp[o+39];
      float a20=sp[o+74], a21=sp[o+75], a22=sp[o+76];
      float gxp = (a02 + 2.f*a12 + a22) - (a00 + 2.f*a10 + a20);
      float gyp = (a20 + 2.f*a21 + a22) - (a00 + 2.f*a01 + a02);
      pv = sqrtf(gxp*gxp + gyp*gyp + 1e-8f);
      float b00=st[o], b01=st[o+1], b02=st[o+2];
      float b10=st[o+37],           b12=st[o+39];
      float b20=st[o+74], b21=st[o+75], b22=st[o+76];
      float gxt = (b02 + 2.f*b12 + b22) - (b00 + 2.f*b10 + b20);
      float gyt = (b20 + 2.f*b21 + b22) - (b00 + 2.f*b01 + b02);
      tv = sqrtf(gxt*gxt + gyt*gyt + 1e-8f);
    }
    pmg[iy*35+ix] = pv; tmg[iy*35+ix] = tv;
  }
  __syncthreads();

  const int ty = tid >> 5, tx = tid & 31;
  const int r0 = ty << 2;

  int c1[10], c2[10], c3[10];
  #pragma unroll
  for (int j = 0; j < 10; j++){
    unsigned w = (unsigned)(mrow[r0 + j] >> tx);
    c3[j] = __popc(w & 0x7Fu);
    c2[j] = __popc((w >> 1) & 0x1Fu);
    c1[j] = __popc((w >> 2) & 0x7u);
  }

  float P[3][3], Q[3][3], A[3][3], B[3][3];
  #pragma unroll
  for (int rr = 0; rr < 3; rr++)
    #pragma unroll
    for (int cc = 0; cc < 3; cc++){
      P[rr][cc] = sp[(r0+1+rr)*37 + tx+1+cc];
      Q[rr][cc] = st[(r0+1+rr)*37 + tx+1+cc];
      A[rr][cc] = pmg[(r0+rr)*35 + tx+cc];
      B[rr][cc] = tmg[(r0+rr)*35 + tx+cc];
    }

  float accg = 0.f, accs = 0.f, accl = 0.f;
  #pragma unroll
  for (int k = 0; k < 4; k++){
    if (k){
      #pragma unroll
      for (int cc = 0; cc < 3; cc++){
        P[0][cc]=P[1][cc]; P[1][cc]=P[2][cc]; P[2][cc]=sp[(r0+k+3)*37 + tx+1+cc];
        Q[0][cc]=Q[1][cc]; Q[1][cc]=Q[2][cc]; Q[2][cc]=st[(r0+k+3)*37 + tx+1+cc];
        A[0][cc]=A[1][cc]; A[1][cc]=A[2][cc]; A[2][cc]=pmg[(r0+k+2)*35 + tx+cc];
        B[0][cc]=B[1][cc]; B[1][cc]=B[2][cc]; B[2][cc]=tmg[(r0+k+2)*35 + tx+cc];
      }
    }
    float gxp = (P[0][2]+2.f*P[1][2]+P[2][2]) - (P[0][0]+2.f*P[1][0]+P[2][0]);
    float gyp = (P[2][0]+2.f*P[2][1]+P[2][2]) - (P[0][0]+2.f*P[0][1]+P[0][2]);
    float cvp = 4.f*P[1][1] - P[0][1] - P[1][0] - P[1][2] - P[2][1];
    float gxt = (Q[0][2]+2.f*Q[1][2]+Q[2][2]) - (Q[0][0]+2.f*Q[1][0]+Q[2][0]);
    float gyt = (Q[2][0]+2.f*Q[2][1]+Q[2][2]) - (Q[0][0]+2.f*Q[0][1]+Q[0][2]);
    float cvt = 4.f*Q[1][1] - Q[0][1] - Q[1][0] - Q[1][2] - Q[2][1];

    float sd = fabsf(A[1][1] - B[1][1]);
    float x1 = gxp + 1e-8f, y1 = gyp;
    float x2 = gxt + 1e-8f, y2 = gyt;
    float dd = fabsf(fast_atan2f(y1*x2 - x1*y2, x1*x2 + y1*y2));
    float cd = fabsf(cvp - cvt);

    int s1 = c1[k+2]+c1[k+3]+c1[k+4];
    int s2 = c2[k+1]+c2[k+2]+c2[k+3]+c2[k+4]+c2[k+5];
    int s3 = c3[k]+c3[k+1]+c3[k+2]+c3[k+3]+c3[k+4]+c3[k+5]+c3[k+6];
    float w1 = (s1 > 0 && s1 <  9) ? 1.f : 0.f;
    float w2 = (s2 > 0 && s2 < 25) ? 1.f : 0.f;
    float w3 = (s3 > 0 && s3 < 49) ? 1.f : 0.f;

    accg += (sd + dd) * (w1 + 0.5f*(w2 + w3)) + cd * (2.f*w1 + w2 + w3);

    float s9 = 0.f, s9q = 0.f;
    #pragma unroll
    for (int rr = 0; rr < 3; rr++)
      #pragma unroll
      for (int cc = 0; cc < 3; cc++){ s9 += P[rr][cc]; s9q += P[rr][cc]*P[rr][cc]; }
    float lm = s9 * (1.f/9.f), lq = s9q * (1.f/9.f);
    accs += sqrtf(fmaxf(lq - lm*lm, 1e-8f)) * w1;

    float psx = (A[0][2]+2.f*A[1][2]+A[2][2]) - (A[0][0]+2.f*A[1][0]+A[2][0]);
    float psy = (A[2][0]+2.f*A[2][1]+A[2][2]) - (A[0][0]+2.f*A[0][1]+A[0][2]);
    float pch = sqrtf(psx*psx + psy*psy + 1e-8f);
    float tsx = (B[0][2]+2.f*B[1][2]+B[2][2]) - (B[0][0]+2.f*B[1][0]+B[2][0]);
    float tsy = (B[2][0]+2.f*B[2][1]+B[2][2]) - (B[0][0]+2.f*B[0][1]+B[0][2]);
    float tch = sqrtf(tsx*tsx + tsy*tsy + 1e-8f);
    accl += fabsf(pch - tch) * w1;
  }

  float g  = block_reduce_add_f(accg, sc);
  float sm = block_reduce_add_f(accs, sc);
  float sl = block_reduce_add_f(accl, sc);
  if (tid == 0){
    int slot = (blockIdx.x + blockIdx.y * 7 + blockIdx.z * 13) & (NSLOT - 1);
    atomicAdd(&acc[0*NSLOT + slot], (double)g);
    atomicAdd(&acc[1*NSLOT + slot], (double)sm);
    atomicAdd(&acc[2*NSLOT + slot], (double)sl);
  }
}

// ---------------------------------------------------------------------------
// Wave-level 1024-pt FFT (verified in R6): 64 (shfl_xor) x 16 (in-register).
// Input: lane q, slot j holds x[j + 16*brev6(q)]. Output: slot j = X[q + 64*j].
// ---------------------------------------------------------------------------
#define FC 0.70710678118654752f
#define FC1 0.92387953251128676f
#define FS1 0.38268343236508977f

__device__ __forceinline__ void bfly(float2& a, float2& b){
  float tx = b.x, ty = b.y;
  b.x = a.x - tx; b.y = a.y - ty;
  a.x += tx;      a.y += ty;
}
__device__ __forceinline__ void cmul_c(float2& b, float wr, float wi){
  float tx = wr*b.x - wi*b.y, ty = wr*b.y + wi*b.x;
  b.x = tx; b.y = ty;
}
__device__ __forceinline__ void rotmi(float2& b){   // b *= -i
  float t = b.x; b.x = b.y; b.y = -t;
}

__device__ __forceinline__ void fft16_reg(float2* v){
  float2 y[16];
  y[0]=v[0];  y[1]=v[8];  y[2]=v[4];  y[3]=v[12];
  y[4]=v[2];  y[5]=v[10]; y[6]=v[6];  y[7]=v[14];
  y[8]=v[1];  y[9]=v[9];  y[10]=v[5]; y[11]=v[13];
  y[12]=v[3]; y[13]=v[11];y[14]=v[7]; y[15]=v[15];
  #pragma unroll
  for (int g = 0; g < 8; g++) bfly(y[2*g], y[2*g+1]);
  #pragma unroll
  for (int g = 0; g < 4; g++){
    int b = 4*g;
    bfly(y[b], y[b+2]);
    rotmi(y[b+3]); bfly(y[b+1], y[b+3]);
  }
  #pragma unroll
  for (int g = 0; g < 2; g++){
    int b = 8*g;
    bfly(y[b], y[b+4]);
    cmul_c(y[b+5],  FC, -FC); bfly(y[b+1], y[b+5]);
    rotmi(y[b+6]);            bfly(y[b+2], y[b+6]);
    cmul_c(y[b+7], -FC, -FC); bfly(y[b+3], y[b+7]);
  }
  bfly(y[0], y[8]);
  cmul_c(y[9],   FC1, -FS1); bfly(y[1], y[9]);
  cmul_c(y[10],  FC,  -FC);  bfly(y[2], y[10]);
  cmul_c(y[11],  FS1, -FC1); bfly(y[3], y[11]);
  rotmi(y[12]);              bfly(y[4], y[12]);
  cmul_c(y[13], -FS1, -FC1); bfly(y[5], y[13]);
  cmul_c(y[14], -FC,  -FC);  bfly(y[6], y[14]);
  cmul_c(y[15], -FC1, -FS1); bfly(y[7], y[15]);
  #pragma unroll
  for (int j = 0; j < 16; j++) v[j] = y[j];
}

__device__ __forceinline__ void fft1024_wave(float2* v, int lane,
                                             const float2* __restrict__ twg){
  #pragma unroll
  for (int s = 0; s < 6; s++){
    const int h = 1 << s;
    const bool up = (lane & h) != 0;
    float2 w = make_float2(1.f, 0.f);
    if (s > 0) w = twg[(lane & (h - 1)) << (9 - s)];
    #pragma unroll
    for (int j = 0; j < 16; j++){
      float ox = __shfl_xor(v[j].x, h, 64);
      float oy = __shfl_xor(v[j].y, h, 64);
      float cx = up ? v[j].x : ox;
      float cy = up ? v[j].y : oy;
      float tx, ty;
      if (s == 0){ tx = cx; ty = cy; }
      else { tx = w.x*cx - w.y*cy; ty = w.x*cy + w.y*cx; }
      v[j].x = up ? (ox - tx) : (v[j].x + tx);
      v[j].y = up ? (oy - ty) : (v[j].y + ty);
    }
  }
  float2 wq = twg[lane];
  float2 cur = make_float2(1.f, 0.f);
  #pragma unroll
  for (int j = 1; j < 16; j++){
    cur = cmulf(cur, wq);
    v[j] = cmulf(v[j], cur);
  }
  fft16_reg(v);
}

// ---------------------------------------------------------------------------
// FFT pass 1 + fused transpose: 512-thr blocks, 8 waves = 8 rows. After the
// wave-FFT, LDS tiles (4 slots x 64 k x [8+1] y) transpose register slots so
// stores are Zt[k][y] with 64 B contiguous segments. Writes Zt directly,
// eliminating the standalone transpose kernel and 16 MB/image of traffic.
// ---------------------------------------------------------------------------
__global__ __launch_bounds__(512)
void fft_rows_t_kernel(const float* __restrict__ pred, const float* __restrict__ targ,
                       float2* __restrict__ Zt, const float2* __restrict__ twg,
                       int img0){
  __shared__ float2 tile[4][64][9];   // [slot][k-lane][y-wave(+pad)]
  const int tid = threadIdx.x;
  const int lane = tid & 63;
  const int w = tid >> 6;            // 0..7 = local row
  const int y0 = blockIdx.x << 3;    // 8 rows per block
  const size_t ibase = ((size_t)(img0 + blockIdx.y) * HW + (y0 + w)) * HW;
  const int rb = __brev(lane) >> 26; // brev6(lane)
  const float4* p4 = (const float4*)(pred + ibase);
  const float4* t4 = (const float4*)(targ + ibase);
  float2 v[16];
  #pragma unroll
  for (int m = 0; m < 4; m++){
    float4 a = p4[4*rb + m];
    float4 b = t4[4*rb + m];
    v[4*m+0] = make_float2(a.x, b.x);
    v[4*m+1] = make_float2(a.y, b.y);
    v[4*m+2] = make_float2(a.z, b.z);
    v[4*m+3] = make_float2(a.w, b.w);
  }
  fft1024_wave(v, lane, twg);

  float2* zb = Zt + (size_t)blockIdx.y * HW * HW;
  const int yl = tid & 7, kl = tid >> 3;     // store mapping: y fastest
  #pragma unroll
  for (int jb = 0; jb < 4; jb++){
    __syncthreads();                          // protect previous tile reads
    #pragma unroll
    for (int jj = 0; jj < 4; jj++) tile[jj][lane][w] = v[4*jb + jj];
    __syncthreads();
    #pragma unroll
    for (int jj = 0; jj < 4; jj++){
      int k = ((jb << 2) + jj) * 64 + kl;
      zb[(size_t)k * HW + y0 + yl] = tile[jj][kl][yl];
    }
  }
}

// ---------------------------------------------------------------------------
// FFT pass 2 + reduce (unchanged from R6): one wave per row-pair (a, -a).
// ---------------------------------------------------------------------------
__device__ __forceinline__ void freq_contrib(float2 Zk, float2 Zm, int k1, int k2,
                                             float& ms, float& ps){
  int di = k1 - 512, dj = k2 - 512;
  if (di*di + dj*dj < 94372) return;         // dist > 307.2  <=>  r2 >= 94372
  float pr = 0.5f*(Zk.x + Zm.x);
  float pi = 0.5f*(Zk.y - Zm.y);
  float tr = 0.5f*(Zk.y + Zm.y);
  float ti = 0.5f*(Zm.x - Zk.x);
  float p2 = pr*pr + pi*pi;
  float t2 = tr*tr + ti*ti;
  ms += p2 + t2 - 2.f*sqrtf(p2*t2);
  float re = pr*tr + pi*ti;
  float im = pi*tr - pr*ti;
  float pd = fast_atan2f(im, re);
  ps += pd*pd;
}

__global__ __launch_bounds__(256)
void fft_cols_reduce_kernel(const float2* __restrict__ Z,
                            const float2* __restrict__ twg,
                            double* __restrict__ acc){
  const int lane = threadIdx.x & 63;
  const int wv = threadIdx.x >> 6;
  const int a = (blockIdx.x << 2) + wv;
  if (a > 512) return;                       // wave-uniform
  const int ap = (1024 - a) & 1023;
  const float2* base = Z + (size_t)blockIdx.y * HW * HW;
  const int rb = __brev(lane) >> 26;

  float2 va[16], vb[16];
  const float4* ra = (const float4*)(base + (size_t)a  * HW);
  const float4* rp = (const float4*)(base + (size_t)ap * HW);
  #pragma unroll
  for (int m = 0; m < 8; m++){
    float4 x = ra[8*rb + m];
    va[2*m]   = make_float2(x.x, x.y);
    va[2*m+1] = make_float2(x.z, x.w);
    float4 yv = rp[8*rb + m];
    vb[2*m]   = make_float2(yv.x, yv.y);
    vb[2*m+1] = make_float2(yv.z, yv.w);
  }
  fft1024_wave(va, lane, twg);
  fft1024_wave(vb, lane, twg);

  float ms = 0.f, ps = 0.f;
  const bool two = (a != ap);
  const int qm = (64 - lane) & 63;
  #pragma unroll
  for (int j = 0; j < 16; j++){
    int k = lane + (j << 6);
    float2 shb = make_float2(__shfl(vb[15-j].x, qm, 64), __shfl(vb[15-j].y, qm, 64));
    float2 vbm = (lane == 0) ? vb[(16-j) & 15] : shb;
    freq_contrib(va[j], vbm, k, a, ms, ps);
    if (two){
      float2 sha = make_float2(__shfl(va[15-j].x, qm, 64), __shfl(va[15-j].y, qm, 64));
      float2 vam = (lane == 0) ? va[(16-j) & 15] : sha;
      freq_contrib(vb[j], vam, k, ap, ms, ps);
    }
  }
  #pragma unroll
  for (int o = 32; o > 0; o >>= 1){
    ms += __shfl_down(ms, o, 64);
    ps += __shfl_down(ps, o, 64);
  }
  if (lane == 0){
    int slot = ((blockIdx.x << 2) + wv + blockIdx.y * 11) & (NSLOT - 1);
    atomicAdd(&acc[3*NSLOT + slot], (double)ms);
    atomicAdd(&acc[4*NSLOT + slot], (double)ps);
  }
}

// ---------------------------------------------------------------------------
__global__ void finalize_kernel(const double* __restrict__ acc, float* __restrict__ out){
  const int t = threadIdx.x;   // 64 threads
  double v[5];
  #pragma unroll
  for (int s = 0; s < 5; s++) v[s] = acc[s*NSLOT + t];
  #pragma unroll
  for (int o = 32; o > 0; o >>= 1)
    #pragma unroll
    for (int s = 0; s < 5; s++) v[s] += __shfl_down(v[s], o, 64);
  if (t == 0){
    const double inv = 1.0 / 8388608.0;      // mean over 8*1024*1024
    double grad   = v[0] * inv / 3.0;        // / len(bms)
    double smooth = v[1] * inv;
    double slope  = v[2] * inv;
    double freq   = (v[3] + 2.0 * v[4]) * inv;
    double total  = 2.0*grad + 1.5*freq + 3.0*smooth + 2.0*slope;
    out[0] = (float)total;
    out[1] = (float)grad;
    out[2] = (float)freq;
    out[3] = (float)smooth;
    out[4] = (float)slope;
  }
}

extern "C" void kernel_launch(void* const* d_in, const int* in_sizes, int n_in,
                              void* d_out, int out_size, void* d_ws, size_t ws_size,
                              hipStream_t stream){
  const float* pred = (const float*)d_in[0];
  const float* targ = (const float*)d_in[1];
  const float* mask = (const float*)d_in[2];
  double* acc = (double*)d_ws;                          // [0, 2560)
  float2* twg = (float2*)((char*)d_ws + 4096);          // [4096, 8192)
  float2* Z   = (float2*)((char*)d_ws + 8192);
  const size_t zimg = (size_t)HW * HW * sizeof(float2); // 8 MiB per image

  int cmax = 1;
  if (ws_size > 8192){
    size_t c = (ws_size - 8192) / zimg;
    if (c > 8) c = 8;
    if (c < 1) c = 1;
    cmax = (int)c;
  }

  setup_kernel<<<2, 256, 0, stream>>>(acc, twg);
  spatial_kernel<<<dim3(32, 32, 8), 256, 0, stream>>>(pred, targ, mask, acc);
  for (int i0 = 0; i0 < 8; i0 += cmax){
    int c = (8 - i0 < cmax) ? (8 - i0) : cmax;
    fft_rows_t_kernel<<<dim3(128, c), 512, 0, stream>>>(pred, targ, Z, twg, i0);
    fft_cols_reduce_kernel<<<dim3(129, c), 256, 0, stream>>>(Z, twg, acc);
  }
  finalize_kernel<<<1, 64, 0, stream>>>(acc, (float*)d_out);
}

// Round 8
// 283.876 us; speedup vs baseline: 1.0787x; 1.0041x over previous
//
#include <hip/hip_runtime.h>
#include <hip/hip_cooperative_groups.h>

namespace cg = cooperative_groups;

#define HW 1024
#define TWO_PI_F 6.28318530717958647692f
#define NSLOT 64   // atomic spreading: 64 slots per accumulator, 5 accumulators

__device__ __forceinline__ float2 cmulf(float2 a, float2 b){
  return make_float2(a.x*b.x - a.y*b.y, a.x*b.y + a.y*b.x);
}

// fast atan2: octant reduction + 9th-order odd minimax poly, max err ~1e-4 rad.
__device__ __forceinline__ float fast_atan2f(float y, float x){
  float ax = fabsf(x), ay = fabsf(y);
  float mx = fmaxf(ax, ay), mn = fminf(ax, ay);
  float a  = mn * __builtin_amdgcn_rcpf(fmaxf(mx, 1e-37f));
  float s  = a * a;
  float r  = ((((0.0208351f*s - 0.085133f)*s + 0.180141f)*s - 0.3302995f)*s
              + 0.999866f) * a;
  r = (ay > ax) ? 1.57079632679f - r : r;
  r = (x < 0.f) ? 3.14159265359f - r : r;
  return (y < 0.f) ? -r : r;
}

// 256-thread block reduction (4 waves of 64), float
__device__ __forceinline__ float block_reduce_add_f(float v, float* sc){
  int tid = threadIdx.x;
  #pragma unroll
  for (int o = 32; o > 0; o >>= 1) v += __shfl_down(v, o, 64);
  __syncthreads();
  if ((tid & 63) == 0) sc[tid >> 6] = v;
  __syncthreads();
  return sc[0] + sc[1] + sc[2] + sc[3];
}

// merged setup: zero accumulators + twiddle table (one launch)
__global__ void setup_kernel(double* acc, float2* twg){
  int i = threadIdx.x + blockIdx.x * 256;   // grid 2 x 256 -> 0..511
  if (i < 5 * NSLOT) acc[i] = 0.0;
  if (i < 512){
    float s, c; sincosf(-TWO_PI_F * (float)i * (1.f/1024.f), &s, &c);
    twg[i] = make_float2(c, s);
  }
}

// ---------------------------------------------------------------------------
// Spatial half (unchanged): 32x32 tile/block, 4 px/thread.
// ---------------------------------------------------------------------------
__global__ __launch_bounds__(256)
void spatial_kernel(const float* __restrict__ pred, const float* __restrict__ targ,
                    const float* __restrict__ mask, double* __restrict__ acc){
  __shared__ float sp[36*37];
  __shared__ float st[36*37];
  __shared__ float smkf[38*39];
  __shared__ unsigned long long mrow[38];
  __shared__ float pmg[34*35];
  __shared__ float tmg[34*35];
  __shared__ float sc[4];

  const int tid = threadIdx.x;
  const int x0 = blockIdx.x << 5, y0 = blockIdx.y << 5;
  const size_t ib = (size_t)blockIdx.z * ((size_t)HW * HW);

  for (int i = tid; i < 1296; i += 256){
    int a = i / 36, b = i % 36;
    int gy = y0 - 2 + a, gx = x0 - 2 + b;
    float pv = 0.f, tv = 0.f;
    if ((unsigned)gy < HW && (unsigned)gx < HW){
      size_t idx = ib + (size_t)gy * HW + gx;
      pv = pred[idx]; tv = targ[idx];
    }
    sp[a*37+b] = pv; st[a*37+b] = tv;
  }
  for (int i = tid; i < 1444; i += 256){
    int a = i / 38, b = i % 38;
    int gy = y0 - 3 + a, gx = x0 - 3 + b;
    float v = 0.f;
    if ((unsigned)gy < HW && (unsigned)gx < HW) v = mask[ib + (size_t)gy * HW + gx];
    smkf[a*39+b] = v;
  }
  __syncthreads();

  if (tid < 38){
    unsigned long long w = 0ull;
    #pragma unroll
    for (int x = 0; x < 38; x++)
      w |= (smkf[tid*39 + x] > 0.5f) ? (1ull << x) : 0ull;
    mrow[tid] = w;
  }

  for (int i = tid; i < 1156; i += 256){
    int iy = i / 34, ix = i % 34;
    int gy = y0 - 1 + iy, gx = x0 - 1 + ix;
    float pv = 0.f, tv = 0.f;
    if ((unsigned)gy < HW && (unsigned)gx < HW){
      int o = (iy)*37 + ix;
      float a00=sp[o], a01=sp[o+1], a02=sp[o+2];
      float a10=sp[o+37],           a12=sp[o+39];
      float a20=sp[o+74], a21=sp[o+75], a22=sp[o+76];
      float gxp = (a02 + 2.f*a12 + a22) - (a00 + 2.f*a10 + a20);
      float gyp = (a20 + 2.f*a21 + a22) - (a00 + 2.f*a01 + a02);
      pv = sqrtf(gxp*gxp + gyp*gyp + 1e-8f);
      float b00=st[o], b01=st[o+1], b02=st[o+2];
      float b10=st[o+37],           b12=st[o+39];
      float b20=st[o+74], b21=st[o+75], b22=st[o+76];
      float gxt = (b02 + 2.f*b12 + b22) - (b00 + 2.f*b10 + b20);
      float gyt = (b20 + 2.f*b21 + b22) - (b00 + 2.f*b01 + b02);
      tv = sqrtf(gxt*gxt + gyt*gyt + 1e-8f);
    }
    pmg[iy*35+ix] = pv; tmg[iy*35+ix] = tv;
  }
  __syncthreads();

  const int ty = tid >> 5, tx = tid & 31;
  const int r0 = ty << 2;

  int c1[10], c2[10], c3[10];
  #pragma unroll
  for (int j = 0; j < 10; j++){
    unsigned w = (unsigned)(mrow[r0 + j] >> tx);
    c3[j] = __popc(w & 0x7Fu);
    c2[j] = __popc((w >> 1) & 0x1Fu);
    c1[j] = __popc((w >> 2) & 0x7u);
  }

  float P[3][3], Q[3][3], A[3][3], B[3][3];
  #pragma unroll
  for (int rr = 0; rr < 3; rr++)
    #pragma unroll
    for (int cc = 0; cc < 3; cc++){
      P[rr][cc] = sp[(r0+1+rr)*37 + tx+1+cc];
      Q[rr][cc] = st[(r0+1+rr)*37 + tx+1+cc];
      A[rr][cc] = pmg[(r0+rr)*35 + tx+cc];
      B[rr][cc] = tmg[(r0+rr)*35 + tx+cc];
    }

  float accg = 0.f, accs = 0.f, accl = 0.f;
  #pragma unroll
  for (int k = 0; k < 4; k++){
    if (k){
      #pragma unroll
      for (int cc = 0; cc < 3; cc++){
        P[0][cc]=P[1][cc]; P[1][cc]=P[2][cc]; P[2][cc]=sp[(r0+k+3)*37 + tx+1+cc];
        Q[0][cc]=Q[1][cc]; Q[1][cc]=Q[2][cc]; Q[2][cc]=st[(r0+k+3)*37 + tx+1+cc];
        A[0][cc]=A[1][cc]; A[1][cc]=A[2][cc]; A[2][cc]=pmg[(r0+k+2)*35 + tx+cc];
        B[0][cc]=B[1][cc]; B[1][cc]=B[2][cc]; B[2][cc]=tmg[(r0+k+2)*35 + tx+cc];
      }
    }
    float gxp = (P[0][2]+2.f*P[1][2]+P[2][2]) - (P[0][0]+2.f*P[1][0]+P[2][0]);
    float gyp = (P[2][0]+2.f*P[2][1]+P[2][2]) - (P[0][0]+2.f*P[0][1]+P[0][2]);
    float cvp = 4.f*P[1][1] - P[0][1] - P[1][0] - P[1][2] - P[2][1];
    float gxt = (Q[0][2]+2.f*Q[1][2]+Q[2][2]) - (Q[0][0]+2.f*Q[1][0]+Q[2][0]);
    float gyt = (Q[2][0]+2.f*Q[2][1]+Q[2][2]) - (Q[0][0]+2.f*Q[0][1]+Q[0][2]);
    float cvt = 4.f*Q[1][1] - Q[0][1] - Q[1][0] - Q[1][2] - Q[2][1];

    float sd = fabsf(A[1][1] - B[1][1]);
    float x1 = gxp + 1e-8f, y1 = gyp;
    float x2 = gxt + 1e-8f, y2 = gyt;
    float dd = fabsf(fast_atan2f(y1*x2 - x1*y2, x1*x2 + y1*y2));
    float cd = fabsf(cvp - cvt);

    int s1 = c1[k+2]+c1[k+3]+c1[k+4];
    int s2 = c2[k+1]+c2[k+2]+c2[k+3]+c2[k+4]+c2[k+5];
    int s3 = c3[k]+c3[k+1]+c3[k+2]+c3[k+3]+c3[k+4]+c3[k+5]+c3[k+6];
    float w1 = (s1 > 0 && s1 <  9) ? 1.f : 0.f;
    float w2 = (s2 > 0 && s2 < 25) ? 1.f : 0.f;
    float w3 = (s3 > 0 && s3 < 49) ? 1.f : 0.f;

    accg += (sd + dd) * (w1 + 0.5f*(w2 + w3)) + cd * (2.f*w1 + w2 + w3);

    float s9 = 0.f, s9q = 0.f;
    #pragma unroll
    for (int rr = 0; rr < 3; rr++)
      #pragma unroll
      for (int cc = 0; cc < 3; cc++){ s9 += P[rr][cc]; s9q += P[rr][cc]*P[rr][cc]; }
    float lm = s9 * (1.f/9.f), lq = s9q * (1.f/9.f);
    accs += sqrtf(fmaxf(lq - lm*lm, 1e-8f)) * w1;

    float psx = (A[0][2]+2.f*A[1][2]+A[2][2]) - (A[0][0]+2.f*A[1][0]+A[2][0]);
    float psy = (A[2][0]+2.f*A[2][1]+A[2][2]) - (A[0][0]+2.f*A[0][1]+A[0][2]);
    float pch = sqrtf(psx*psx + psy*psy + 1e-8f);
    float tsx = (B[0][2]+2.f*B[1][2]+B[2][2]) - (B[0][0]+2.f*B[1][0]+B[2][0]);
    float tsy = (B[2][0]+2.f*B[2][1]+B[2][2]) - (B[0][0]+2.f*B[0][1]+B[0][2]);
    float tch = sqrtf(tsx*tsx + tsy*tsy + 1e-8f);
    accl += fabsf(pch - tch) * w1;
  }

  float g  = block_reduce_add_f(accg, sc);
  float sm = block_reduce_add_f(accs, sc);
  float sl = block_reduce_add_f(accl, sc);
  if (tid == 0){
    int slot = (blockIdx.x + blockIdx.y * 7 + blockIdx.z * 13) & (NSLOT - 1);
    atomicAdd(&acc[0*NSLOT + slot], (double)g);
    atomicAdd(&acc[1*NSLOT + slot], (double)sm);
    atomicAdd(&acc[2*NSLOT + slot], (double)sl);
  }
}

// ---------------------------------------------------------------------------
// Wave-level 1024-pt FFT (verified): 64 (shfl_xor) x 16 (in-register).
// Input: lane q, slot j holds x[j + 16*brev6(q)]. Output: slot j = X[q + 64*j].
// ---------------------------------------------------------------------------
#define FC 0.70710678118654752f
#define FC1 0.92387953251128676f
#define FS1 0.38268343236508977f

__device__ __forceinline__ void bfly(float2& a, float2& b){
  float tx = b.x, ty = b.y;
  b.x = a.x - tx; b.y = a.y - ty;
  a.x += tx;      a.y += ty;
}
__device__ __forceinline__ void cmul_c(float2& b, float wr, float wi){
  float tx = wr*b.x - wi*b.y, ty = wr*b.y + wi*b.x;
  b.x = tx; b.y = ty;
}
__device__ __forceinline__ void rotmi(float2& b){   // b *= -i
  float t = b.x; b.x = b.y; b.y = -t;
}

__device__ __forceinline__ void fft16_reg(float2* v){
  float2 y[16];
  y[0]=v[0];  y[1]=v[8];  y[2]=v[4];  y[3]=v[12];
  y[4]=v[2];  y[5]=v[10]; y[6]=v[6];  y[7]=v[14];
  y[8]=v[1];  y[9]=v[9];  y[10]=v[5]; y[11]=v[13];
  y[12]=v[3]; y[13]=v[11];y[14]=v[7]; y[15]=v[15];
  #pragma unroll
  for (int g = 0; g < 8; g++) bfly(y[2*g], y[2*g+1]);
  #pragma unroll
  for (int g = 0; g < 4; g++){
    int b = 4*g;
    bfly(y[b], y[b+2]);
    rotmi(y[b+3]); bfly(y[b+1], y[b+3]);
  }
  #pragma unroll
  for (int g = 0; g < 2; g++){
    int b = 8*g;
    bfly(y[b], y[b+4]);
    cmul_c(y[b+5],  FC, -FC); bfly(y[b+1], y[b+5]);
    rotmi(y[b+6]);            bfly(y[b+2], y[b+6]);
    cmul_c(y[b+7], -FC, -FC); bfly(y[b+3], y[b+7]);
  }
  bfly(y[0], y[8]);
  cmul_c(y[9],   FC1, -FS1); bfly(y[1], y[9]);
  cmul_c(y[10],  FC,  -FC);  bfly(y[2], y[10]);
  cmul_c(y[11],  FS1, -FC1); bfly(y[3], y[11]);
  rotmi(y[12]);              bfly(y[4], y[12]);
  cmul_c(y[13], -FS1, -FC1); bfly(y[5], y[13]);
  cmul_c(y[14], -FC,  -FC);  bfly(y[6], y[14]);
  cmul_c(y[15], -FC1, -FS1); bfly(y[7], y[15]);
  #pragma unroll
  for (int j = 0; j < 16; j++) v[j] = y[j];
}

__device__ __forceinline__ void fft1024_wave(float2* v, int lane,
                                             const float2* __restrict__ twg){
  #pragma unroll
  for (int s = 0; s < 6; s++){
    const int h = 1 << s;
    const bool up = (lane & h) != 0;
    float2 w = make_float2(1.f, 0.f);
    if (s > 0) w = twg[(lane & (h - 1)) << (9 - s)];
    #pragma unroll
    for (int j = 0; j < 16; j++){
      float ox = __shfl_xor(v[j].x, h, 64);
      float oy = __shfl_xor(v[j].y, h, 64);
      float cx = up ? v[j].x : ox;
      float cy = up ? v[j].y : oy;
      float tx, ty;
      if (s == 0){ tx = cx; ty = cy; }
      else { tx = w.x*cx - w.y*cy; ty = w.x*cy + w.y*cx; }
      v[j].x = up ? (ox - tx) : (v[j].x + tx);
      v[j].y = up ? (oy - ty) : (v[j].y + ty);
    }
  }
  float2 wq = twg[lane];
  float2 cur = make_float2(1.f, 0.f);
  #pragma unroll
  for (int j = 1; j < 16; j++){
    cur = cmulf(cur, wq);
    v[j] = cmulf(v[j], cur);
  }
  fft16_reg(v);
}

// ---------------------------------------------------------------------------
// Row-FFT task body: FFT one row, transposed store into Zt (one image buffer).
// Block-cooperative (8 waves = 8 rows); uses the shared tile.
// ---------------------------------------------------------------------------
__device__ __forceinline__ void rows_task(const float* __restrict__ pred,
                                          const float* __restrict__ targ,
                                          float2* __restrict__ zb,
                                          const float2* __restrict__ twg,
                                          int img, int y0,
                                          float2 (*tile)[64][9]){
  const int tid = threadIdx.x;
  const int lane = tid & 63;
  const int w = tid >> 6;
  const size_t ibase = ((size_t)img * HW + (y0 + w)) * HW;
  const int rb = __brev(lane) >> 26;
  const float4* p4 = (const float4*)(pred + ibase);
  const float4* t4 = (const float4*)(targ + ibase);
  float2 v[16];
  #pragma unroll
  for (int m = 0; m < 4; m++){
    float4 a = p4[4*rb + m];
    float4 b = t4[4*rb + m];
    v[4*m+0] = make_float2(a.x, b.x);
    v[4*m+1] = make_float2(a.y, b.y);
    v[4*m+2] = make_float2(a.z, b.z);
    v[4*m+3] = make_float2(a.w, b.w);
  }
  fft1024_wave(v, lane, twg);
  const int yl = tid & 7, kl = tid >> 3;
  #pragma unroll
  for (int jb = 0; jb < 4; jb++){
    __syncthreads();
    #pragma unroll
    for (int jj = 0; jj < 4; jj++) tile[jj][lane][w] = v[4*jb + jj];
    __syncthreads();
    #pragma unroll
    for (int jj = 0; jj < 4; jj++){
      int k = ((jb << 2) + jj) * 64 + kl;
      zb[(size_t)k * HW + y0 + yl] = tile[jj][kl][yl];
    }
  }
}

// ---------------------------------------------------------------------------
// Col-FFT + reduce task body: one wave handles row-pair (a, -a) of Zt.
// ---------------------------------------------------------------------------
__device__ __forceinline__ void freq_contrib(float2 Zk, float2 Zm, int k1, int k2,
                                             float& ms, float& ps){
  int di = k1 - 512, dj = k2 - 512;
  if (di*di + dj*dj < 94372) return;         // dist > 307.2  <=>  r2 >= 94372
  float pr = 0.5f*(Zk.x + Zm.x);
  float pi = 0.5f*(Zk.y - Zm.y);
  float tr = 0.5f*(Zk.y + Zm.y);
  float ti = 0.5f*(Zm.x - Zk.x);
  float p2 = pr*pr + pi*pi;
  float t2 = tr*tr + ti*ti;
  ms += p2 + t2 - 2.f*sqrtf(p2*t2);
  float re = pr*tr + pi*ti;
  float im = pi*tr - pr*ti;
  float pd = fast_atan2f(im, re);
  ps += pd*pd;
}

__device__ __forceinline__ void cols_task(const float2* __restrict__ base,
                                          const float2* __restrict__ twg,
                                          double* __restrict__ acc,
                                          int a, int slot){
  const int lane = threadIdx.x & 63;
  const int ap = (1024 - a) & 1023;
  const int rb = __brev(lane) >> 26;
  float2 va[16], vb[16];
  const float4* ra = (const float4*)(base + (size_t)a  * HW);
  const float4* rp = (const float4*)(base + (size_t)ap * HW);
  #pragma unroll
  for (int m = 0; m < 8; m++){
    float4 x = ra[8*rb + m];
    va[2*m]   = make_float2(x.x, x.y);
    va[2*m+1] = make_float2(x.z, x.w);
    float4 yv = rp[8*rb + m];
    vb[2*m]   = make_float2(yv.x, yv.y);
    vb[2*m+1] = make_float2(yv.z, yv.w);
  }
  fft1024_wave(va, lane, twg);
  fft1024_wave(vb, lane, twg);

  float ms = 0.f, ps = 0.f;
  const bool two = (a != ap);
  const int qm = (64 - lane) & 63;
  #pragma unroll
  for (int j = 0; j < 16; j++){
    int k = lane + (j << 6);
    float2 shb = make_float2(__shfl(vb[15-j].x, qm, 64), __shfl(vb[15-j].y, qm, 64));
    float2 vbm = (lane == 0) ? vb[(16-j) & 15] : shb;
    freq_contrib(va[j], vbm, k, a, ms, ps);
    if (two){
      float2 sha = make_float2(__shfl(va[15-j].x, qm, 64), __shfl(va[15-j].y, qm, 64));
      float2 vam = (lane == 0) ? va[(16-j) & 15] : sha;
      freq_contrib(vb[j], vam, k, ap, ms, ps);
    }
  }
  #pragma unroll
  for (int o = 32; o > 0; o >>= 1){
    ms += __shfl_down(ms, o, 64);
    ps += __shfl_down(ps, o, 64);
  }
  if (lane == 0){
    atomicAdd(&acc[3*NSLOT + slot], (double)ms);
    atomicAdd(&acc[4*NSLOT + slot], (double)ps);
  }
}

// ---------------------------------------------------------------------------
// Cooperative pipelined FFT: 386 blocks x 512 thr. Blocks 0..255 produce row
// FFTs (2 images/phase into a 4-image ring of Zt buffers); blocks 256..385
// consume the previous phase's 2 images (col FFT + reduce). grid.sync()
// separates the 5 phases. Replaces up to 16 serial starved dispatches.
// ---------------------------------------------------------------------------
__global__ __launch_bounds__(512)
void fft_coop_kernel(const float* __restrict__ pred, const float* __restrict__ targ,
                     float2* __restrict__ Zbuf, const float2* __restrict__ twg,
                     double* __restrict__ acc){
  cg::grid_group grid = cg::this_grid();
  __shared__ float2 tile[4][64][9];
  const int w = threadIdx.x >> 6;
  const int bi = blockIdx.x;

  for (int p = 0; p < 5; p++){
    if (p < 4 && bi < 256){
      // rows: images {2p, 2p+1}; 128 blocks per image, 8 rows/block
      int img = 2*p + (bi >> 7);
      int y0 = (bi & 127) << 3;
      float2* zb = Zbuf + (size_t)(img & 3) * HW * HW;
      rows_task(pred, targ, zb, twg, img, y0, tile);
    }
    if (p >= 1 && bi >= 256){
      // cols: images {2p-2, 2p-1}; 513 pair-tasks per image
      int idx = ((bi - 256) << 3) + w;        // 0..1039
      if (idx < 1026){
        int sub = (idx >= 513) ? 1 : 0;
        int a = idx - 513 * sub;
        int img = 2*(p-1) + sub;
        const float2* base = Zbuf + (size_t)(img & 3) * HW * HW;
        cols_task(base, twg, acc, a, (idx + p*13) & (NSLOT - 1));
      }
    }
    grid.sync();
  }
}

// ---------------------------------------------------------------------------
// Fallback (R7 path) kernels for small workspace / no cooperative support.
// ---------------------------------------------------------------------------
__global__ __launch_bounds__(512)
void fft_rows_t_kernel(const float* __restrict__ pred, const float* __restrict__ targ,
                       float2* __restrict__ Zt, const float2* __restrict__ twg,
                       int img0){
  __shared__ float2 tile[4][64][9];
  float2* zb = Zt + (size_t)blockIdx.y * HW * HW;
  rows_task(pred, targ, zb, twg, img0 + blockIdx.y, blockIdx.x << 3, tile);
}

__global__ __launch_bounds__(256)
void fft_cols_reduce_kernel(const float2* __restrict__ Z,
                            const float2* __restrict__ twg,
                            double* __restrict__ acc){
  const int wv = threadIdx.x >> 6;
  const int a = (blockIdx.x << 2) + wv;
  if (a > 512) return;                       // wave-uniform
  const float2* base = Z + (size_t)blockIdx.y * HW * HW;
  cols_task(base, twg, acc, a, (a + blockIdx.y * 11) & (NSLOT - 1));
}

// ---------------------------------------------------------------------------
__global__ void finalize_kernel(const double* __restrict__ acc, float* __restrict__ out){
  const int t = threadIdx.x;   // 64 threads
  double v[5];
  #pragma unroll
  for (int s = 0; s < 5; s++) v[s] = acc[s*NSLOT + t];
  #pragma unroll
  for (int o = 32; o > 0; o >>= 1)
    #pragma unroll
    for (int s = 0; s < 5; s++) v[s] += __shfl_down(v[s], o, 64);
  if (t == 0){
    const double inv = 1.0 / 8388608.0;      // mean over 8*1024*1024
    double grad   = v[0] * inv / 3.0;        // / len(bms)
    double smooth = v[1] * inv;
    double slope  = v[2] * inv;
    double freq   = (v[3] + 2.0 * v[4]) * inv;
    double total  = 2.0*grad + 1.5*freq + 3.0*smooth + 2.0*slope;
    out[0] = (float)total;
    out[1] = (float)grad;
    out[2] = (float)freq;
    out[3] = (float)smooth;
    out[4] = (float)slope;
  }
}

extern "C" void kernel_launch(void* const* d_in, const int* in_sizes, int n_in,
                              void* d_out, int out_size, void* d_ws, size_t ws_size,
                              hipStream_t stream){
  const float* pred = (const float*)d_in[0];
  const float* targ = (const float*)d_in[1];
  const float* mask = (const float*)d_in[2];
  double* acc = (double*)d_ws;                          // [0, 2560)
  float2* twg = (float2*)((char*)d_ws + 4096);          // [4096, 8192)
  float2* Z   = (float2*)((char*)d_ws + 8192);
  const size_t zimg = (size_t)HW * HW * sizeof(float2); // 8 MiB per image

  setup_kernel<<<2, 256, 0, stream>>>(acc, twg);
  spatial_kernel<<<dim3(32, 32, 8), 256, 0, stream>>>(pred, targ, mask, acc);

  // cooperative pipelined path: needs 4 image buffers + co-residency of 386 blocks
  bool coop = false;
  if (ws_size >= 8192 + 4 * zimg){
    int mb = 0;
    if (hipOccupancyMaxActiveBlocksPerMultiprocessor(&mb, fft_coop_kernel, 512, 0)
          == hipSuccess && mb * 256 >= 386){
      void* args[] = {(void*)&pred, (void*)&targ, (void*)&Z, (void*)&twg, (void*)&acc};
      if (hipLaunchCooperativeKernel((void*)fft_coop_kernel, dim3(386), dim3(512),
                                     args, 0, stream) == hipSuccess)
        coop = true;
    }
  }
  if (!coop){
    int cmax = 1;
    if (ws_size > 8192){
      size_t c = (ws_size - 8192) / zimg;
      if (c > 8) c = 8;
      if (c < 1) c = 1;
      cmax = (int)c;
    }
    for (int i0 = 0; i0 < 8; i0 += cmax){
      int c = (8 - i0 < cmax) ? (8 - i0) : cmax;
      fft_rows_t_kernel<<<dim3(128, c), 512, 0, stream>>>(pred, targ, Z, twg, i0);
      fft_cols_reduce_kernel<<<dim3(129, c), 256, 0, stream>>>(Z, twg, acc);
    }
  }
  finalize_kernel<<<1, 64, 0, stream>>>(acc, (float*)d_out);
}